// Round 6
// baseline (39.415 us; speedup 1.0000x reference)
//
#include <hip/hip_runtime.h>

// Problem constants (from reference):
//   RAW_NODES = 10242, NEW_NODES = 4*10242-6 = 40962, B=8, C=128
//   x: (B, C, RAW) f32
//   out: (B, C, NOUT) f32 = concat( x[:,:,top//7],  mean-pairs of x[:,:,down//7] )
#define RAW    10242
#define LDSN   10240   // floats per row staged in LDS (40960 B)
#define NOUT   40962
#define NPAIR  30720   // NOUT - RAW
#define BC     1024    // B * C
#define TPB    1024

// R5 post-mortem: index-dedup gained 1.1us (not 4-9); we're at ~5.5 TB/s
// (~88% of mixed-stream ceiling). R6: same 2-row/block structure but
// TPB 512 -> 1024: LDS still 81920 B -> 2 blocks/CU (160 KiB exact),
// waves/CU 16 -> 32 (100% occupancy) to hide store + LDS-gather latency.
__global__ __launch_bounds__(TPB, 8) void upconv_layer_batch_average_kernel(
    const float* __restrict__ x,
    const int*   __restrict__ top,     // RAW entries, value in [0, 7*RAW)
    const int*   __restrict__ down,    // 2*NPAIR entries
    float*       __restrict__ out)
{
    __shared__ float lds[2][LDSN];     // 81920 B -> 2 blocks/CU

    const int r0 = blockIdx.x * 2;     // rows r0, r0+1
    const float* __restrict__ xr0 = x + (size_t)r0 * RAW;
    const float* __restrict__ xr1 = xr0 + RAW;
    float* __restrict__ o0 = out + (size_t)r0 * (size_t)NOUT;
    float* __restrict__ o1 = o0 + NOUT;

    // --- Stage first 10240 floats of each row (float2; bases 8B-aligned).
    // 5120 float2 per row = 5 iters of 1024 threads.
    const float2* __restrict__ x02 = (const float2*)xr0;
    const float2* __restrict__ x12 = (const float2*)xr1;
    float2* l02 = (float2*)lds[0];
    float2* l12 = (float2*)lds[1];
    #pragma unroll
    for (int i = 0; i < 5; ++i) {
        int idx = i * TPB + threadIdx.x;
        l02[idx] = x02[idx];
        l12[idx] = x12[idx];
    }
    __syncthreads();

    // --- Region 1: 5121 int2 index-pairs cover all 10242 entries.
    const int2* __restrict__ top2 = (const int2*)top;
    float2* __restrict__ o0_2 = (float2*)o0;
    float2* __restrict__ o1_2 = (float2*)o1;
    for (int p = threadIdx.x; p < RAW / 2 + 1; p += TPB) {   // 5121
        int2 t = top2[p];
        unsigned s0 = (unsigned)t.x / 7u;
        unsigned s1 = (unsigned)t.y / 7u;
        unsigned mx = s0 > s1 ? s0 : s1;
        float2 a, b;
        if (__builtin_expect(mx >= (unsigned)LDSN, 0)) {
            // rare (~0.02%/index): tail elements live only in global (L2-hot)
            a.x = xr0[s0]; a.y = xr0[s1];
            b.x = xr1[s0]; b.y = xr1[s1];
        } else {
            a.x = lds[0][s0]; a.y = lds[0][s1];
            b.x = lds[1][s0]; b.y = lds[1][s1];
        }
        o0_2[p] = a;
        o1_2[p] = b;
    }

    // --- Region 2: 15360 int4 loads (4 indices = 2 outputs) x 2 rows.
    // 15360 = 15 * 1024 exactly.
    const int4* __restrict__ d4 = (const int4*)down;
    float2* __restrict__ od0 = (float2*)(o0 + RAW);
    float2* __restrict__ od1 = (float2*)(o1 + RAW);
    for (int m = threadIdx.x; m < NPAIR / 2; m += TPB) {
        int4 d = d4[m];
        unsigned s0 = (unsigned)d.x / 7u;
        unsigned s1 = (unsigned)d.y / 7u;
        unsigned s2 = (unsigned)d.z / 7u;
        unsigned s3 = (unsigned)d.w / 7u;
        unsigned m01 = s0 > s1 ? s0 : s1;
        unsigned m23 = s2 > s3 ? s2 : s3;
        unsigned mx  = m01 > m23 ? m01 : m23;
        float2 a, b;
        if (__builtin_expect(mx >= (unsigned)LDSN, 0)) {
            a.x = 0.5f * (xr0[s0] + xr0[s1]); a.y = 0.5f * (xr0[s2] + xr0[s3]);
            b.x = 0.5f * (xr1[s0] + xr1[s1]); b.y = 0.5f * (xr1[s2] + xr1[s3]);
        } else {
            a.x = 0.5f * (lds[0][s0] + lds[0][s1]); a.y = 0.5f * (lds[0][s2] + lds[0][s3]);
            b.x = 0.5f * (lds[1][s0] + lds[1][s1]); b.y = 0.5f * (lds[1][s2] + lds[1][s3]);
        }
        od0[m] = a;
        od1[m] = b;
    }
}

extern "C" void kernel_launch(void* const* d_in, const int* in_sizes, int n_in,
                              void* d_out, int out_size, void* d_ws, size_t ws_size,
                              hipStream_t stream) {
    const float* x    = (const float*)d_in[0];
    const int*   top  = (const int*)d_in[1];
    const int*   down = (const int*)d_in[2];
    float*       out  = (float*)d_out;

    upconv_layer_batch_average_kernel<<<dim3(BC / 2), TPB, 0, stream>>>(x, top, down, out);
}

// Round 7
// 38.090 us; speedup vs baseline: 1.0348x; 1.0348x over previous
//
#include <hip/hip_runtime.h>

// Problem constants (from reference):
//   RAW_NODES = 10242, NEW_NODES = 4*10242-6 = 40962, B=8, C=128
//   x: (B, C, RAW) f32
//   out: (B, C, NOUT) f32 = concat( x[:,:,top//7],  mean-pairs of x[:,:,down//7] )
#define RAW    10242
#define LDSN   10240   // floats per row staged in LDS (40960 B)
#define NOUT   40962
#define NPAIR  30720   // NOUT - RAW
#define BC     1024    // B * C
#define TPB    512

// FINAL (reverted to R5 best): 2 rows/block, TPB=512, LDS 81920 B ->
// 2 blocks/CU (160 KiB exact), grid 512 = 2/CU zero-tail. 38.1 us =
// ~5.5 TB/s mixed r/w (~88% of 6.3 TB/s copy ceiling). R6 showed more
// waves/CU (32) regress; R4 showed branchless tail-select regresses.
// Traffic is within ~2% of compulsory: 42 MB read + 168 MB write.
__global__ __launch_bounds__(TPB, 4) void upconv_layer_batch_average_kernel(
    const float* __restrict__ x,
    const int*   __restrict__ top,     // RAW entries, value in [0, 7*RAW)
    const int*   __restrict__ down,    // 2*NPAIR entries
    float*       __restrict__ out)
{
    __shared__ float lds[2][LDSN];     // 81920 B -> 2 blocks/CU

    const int r0 = blockIdx.x * 2;     // rows r0, r0+1
    const float* __restrict__ xr0 = x + (size_t)r0 * RAW;
    const float* __restrict__ xr1 = xr0 + RAW;
    float* __restrict__ o0 = out + (size_t)r0 * (size_t)NOUT;
    float* __restrict__ o1 = o0 + NOUT;

    // --- Stage first 10240 floats of each row (float2; bases 8B-aligned).
    // 5120 float2 per row = 10 iters of 512 threads.
    const float2* __restrict__ x02 = (const float2*)xr0;
    const float2* __restrict__ x12 = (const float2*)xr1;
    float2* l02 = (float2*)lds[0];
    float2* l12 = (float2*)lds[1];
    #pragma unroll
    for (int i = 0; i < 10; ++i) {
        int idx = i * TPB + threadIdx.x;
        l02[idx] = x02[idx];
        l12[idx] = x12[idx];
    }
    __syncthreads();

    // --- Region 1: 5121 int2 index-pairs cover all 10242 entries.
    const int2* __restrict__ top2 = (const int2*)top;
    float2* __restrict__ o0_2 = (float2*)o0;
    float2* __restrict__ o1_2 = (float2*)o1;
    for (int p = threadIdx.x; p < RAW / 2 + 1; p += TPB) {   // 5121
        int2 t = top2[p];
        unsigned s0 = (unsigned)t.x / 7u;
        unsigned s1 = (unsigned)t.y / 7u;
        unsigned mx = s0 > s1 ? s0 : s1;
        float2 a, b;
        if (__builtin_expect(mx >= (unsigned)LDSN, 0)) {
            // rare (~0.02%/index): tail elements live only in global (L2-hot)
            a.x = xr0[s0]; a.y = xr0[s1];
            b.x = xr1[s0]; b.y = xr1[s1];
        } else {
            a.x = lds[0][s0]; a.y = lds[0][s1];
            b.x = lds[1][s0]; b.y = lds[1][s1];
        }
        o0_2[p] = a;
        o1_2[p] = b;
    }

    // --- Region 2: 15360 int4 loads (4 indices = 2 outputs) x 2 rows.
    // 15360 = 30 * 512 exactly.
    const int4* __restrict__ d4 = (const int4*)down;
    float2* __restrict__ od0 = (float2*)(o0 + RAW);
    float2* __restrict__ od1 = (float2*)(o1 + RAW);
    for (int m = threadIdx.x; m < NPAIR / 2; m += TPB) {
        int4 d = d4[m];
        unsigned s0 = (unsigned)d.x / 7u;
        unsigned s1 = (unsigned)d.y / 7u;
        unsigned s2 = (unsigned)d.z / 7u;
        unsigned s3 = (unsigned)d.w / 7u;
        unsigned m01 = s0 > s1 ? s0 : s1;
        unsigned m23 = s2 > s3 ? s2 : s3;
        unsigned mx  = m01 > m23 ? m01 : m23;
        float2 a, b;
        if (__builtin_expect(mx >= (unsigned)LDSN, 0)) {
            a.x = 0.5f * (xr0[s0] + xr0[s1]); a.y = 0.5f * (xr0[s2] + xr0[s3]);
            b.x = 0.5f * (xr1[s0] + xr1[s1]); b.y = 0.5f * (xr1[s2] + xr1[s3]);
        } else {
            a.x = 0.5f * (lds[0][s0] + lds[0][s1]); a.y = 0.5f * (lds[0][s2] + lds[0][s3]);
            b.x = 0.5f * (lds[1][s0] + lds[1][s1]); b.y = 0.5f * (lds[1][s2] + lds[1][s3]);
        }
        od0[m] = a;
        od1[m] = b;
    }
}

extern "C" void kernel_launch(void* const* d_in, const int* in_sizes, int n_in,
                              void* d_out, int out_size, void* d_ws, size_t ws_size,
                              hipStream_t stream) {
    const float* x    = (const float*)d_in[0];
    const int*   top  = (const int*)d_in[1];
    const int*   down = (const int*)d_in[2];
    float*       out  = (float*)d_out;

    upconv_layer_batch_average_kernel<<<dim3(BC / 2), TPB, 0, stream>>>(x, top, down, out);
}